// Round 12
// baseline (236.771 us; speedup 1.0000x reference)
//
#include <hip/hip_runtime.h>
#include <hip/hip_bf16.h>

#define N_CTX 4096
#define NH    16
#define DH    64
#define DIM   1024   // NH * DH
#define NSPLIT 4
#define KT_PER_SPLIT (N_CTX / 64 / NSPLIT)   // 16

typedef __attribute__((ext_vector_type(8))) short bf16x8;  // 8 bf16 in 4 VGPRs
typedef __attribute__((ext_vector_type(4))) float f32x4;   // MFMA C/D
typedef __attribute__((ext_vector_type(2))) unsigned u32x2;

// RNE float->bf16 (non-hot paths)
__device__ __forceinline__ ushort f2bf(float f) {
    union { float f; unsigned u; } x; x.f = f;
    unsigned r = (x.u + 0x7FFFu + ((x.u >> 16) & 1u)) >> 16;
    return (ushort)r;
}
__device__ __forceinline__ float bf2f(ushort u) {
    union { unsigned u; float f; } x; x.u = ((unsigned)u) << 16; return x.f;
}
__device__ __forceinline__ unsigned fbits(float f) {
    union { float f; unsigned u; } x; x.f = f; return x.u;
}
// pack two floats to packed bf16 pair (round-half-up), 3 VALU ops.
// VERIFIED R0-R11.  Failed experiments, do not repeat:
//   R7:  v_cvt_pk_bf16_f32 swap — absmax 20x regression (semantics mismatch).
//   R10: l via ones-MFMA — VGPR 112->156, occupancy 19->11%, +27 µs.
__device__ __forceinline__ unsigned pack_bf16(float lo, float hi) {
    unsigned a = fbits(lo) + 0x8000u;
    unsigned b = fbits(hi) + 0x8000u;
#if defined(__has_builtin)
#if __has_builtin(__builtin_amdgcn_perm)
    return __builtin_amdgcn_perm(b, a, 0x07060302u);
#else
    return (a >> 16) | (b & 0xFFFF0000u);
#endif
#else
    return (a >> 16) | (b & 0xFFFF0000u);
#endif
}
__device__ __forceinline__ float fast_exp2(float x) {
#if defined(__has_builtin)
#if __has_builtin(__builtin_amdgcn_exp2f)
    return __builtin_amdgcn_exp2f(x);
#else
    return exp2f(x);
#endif
#else
    return exp2f(x);
#endif
}
// hw sin/cos of x (radians): revolutions + v_fract + v_sin/v_cos.
__device__ __forceinline__ void fast_sincos(float ang, float* s, float* c) {
#if defined(__has_builtin)
#if __has_builtin(__builtin_amdgcn_sinf) && __has_builtin(__builtin_amdgcn_cosf) && __has_builtin(__builtin_amdgcn_fractf)
    float rev = __builtin_amdgcn_fractf(ang * 0.15915494309189535f);
    *s = __builtin_amdgcn_sinf(rev);
    *c = __builtin_amdgcn_cosf(rev);
    return;
#endif
#endif
    sincosf(ang, s, c);
}

// Cross-lane row swaps (gfx950 VALU ops, 2 outputs per instruction).
__device__ __forceinline__ void pl32_swap(unsigned &a, unsigned &b) {
#if defined(__has_builtin)
#if __has_builtin(__builtin_amdgcn_permlane32_swap)
    u32x2 r = __builtin_amdgcn_permlane32_swap(a, b, false, false);
    a = r[0]; b = r[1];
    return;
#endif
#endif
    const int lane = (int)(threadIdx.x & 63);
    unsigned ax = (unsigned)__shfl_xor((int)a, 32, 64);
    unsigned bx = (unsigned)__shfl_xor((int)b, 32, 64);
    unsigned na = (lane & 32) ? bx : a;
    unsigned nb = (lane & 32) ? b  : ax;
    a = na; b = nb;
}
__device__ __forceinline__ void pl16_swap(unsigned &a, unsigned &b) {
#if defined(__has_builtin)
#if __has_builtin(__builtin_amdgcn_permlane16_swap)
    u32x2 r = __builtin_amdgcn_permlane16_swap(a, b, false, false);
    a = r[0]; b = r[1];
    return;
#endif
#endif
    const int lane = (int)(threadIdx.x & 63);
    unsigned ax = (unsigned)__shfl_xor((int)a, 16, 64);
    unsigned bx = (unsigned)__shfl_xor((int)b, 16, 64);
    unsigned na = (lane & 16) ? bx : a;
    unsigned nb = (lane & 16) ? b  : ax;
    a = na; b = nb;
}

// 0.125 * log2(e): folded into Q during prep; softmax shift-invariance lets us
// drop the bias term entirely (p = exp2(s) directly, p <= 2^18.1).
#define SC 0.18033688011112042f
// log2(10000)/32
#define LF 0.4152410118609203f

// ---------------------------------------------------------------------------
// front (fused): prep-q | prep-k | vtrans | wconv in ONE launch (R9).
//   bid [0,16384)      : prep q  (premul SC)
//   bid [16384,32768)  : prep k
//   bid [32768,33792)  : vtrans (kt = b&63, h = b>>6)
//   bid [33792,34816)  : wconv
// ---------------------------------------------------------------------------
__global__ __launch_bounds__(256) void front_kernel(
    const float* __restrict__ qg, const float* __restrict__ kg,
    const float* __restrict__ v,  const float* __restrict__ w,
    const float* __restrict__ qk_scale,
    ushort* __restrict__ qb, ushort* __restrict__ kb,
    ushort* __restrict__ vt, ushort* __restrict__ wb)
{
    __shared__ ushort L[64][68];
    const int bid = blockIdx.x;
    const int t   = threadIdx.x;

    if (bid < 32768) {
        // ---- prep (R5-verified body: per-thread sincos) ----
        const int isk  = bid >> 14;
        const int bx   = bid & 16383;
        const int lane = t & 63;
        const int wave = t >> 6;
        const int row  = bx * 4 + wave;   // row = n*NH + h
        const int n = row >> 4;
        const int h = row & 15;
        const float* __restrict__ x = isk ? kg : qg;
        ushort* __restrict__ xb = isk ? kb : qb;
        const float premul = isk ? 1.0f : SC;

        float val = x[(size_t)n * DIM + h * DH + lane];
        float other = __shfl_xor(val, 1, 64);

        const int i = lane >> 1;
        float inv_freq = fast_exp2((float)i * -LF);   // 10000^(-i/32)
        float ang = (float)n * inv_freq;
        float s, c;
        fast_sincos(ang, &s, &c);

        float r = (lane & 1) ? fmaf(other, s, val * c)
                             : fmaf(val, c, -(other * s));

        float ss = r * r;
        #pragma unroll
        for (int off = 32; off > 0; off >>= 1)
            ss += __shfl_xor(ss, off, 64);
        float invn = rsqrtf(fmaxf(ss, 1e-24f));
        float scl  = qk_scale[lane] * premul;

        xb[((size_t)h * N_CTX + n) * DH + lane] = f2bf(r * invn * scl);
    } else if (bid < 33792) {
        // ---- vtrans: v (N, DIM) fp32 -> vt bf16 [h][d][n] ----
        const int b2 = bid - 32768;
        const int kt = b2 & 63, h = b2 >> 6;

        for (int e = t; e < 4096; e += 256) {
            int key = e >> 6, d = e & 63;
            float f = v[(size_t)(kt * 64 + key) * DIM + h * DH + d];
            L[d][key] = f2bf(f);
        }
        __syncthreads();
        for (int e = t; e < 4096; e += 256) {
            int d = e >> 6, key = e & 63;
            vt[((size_t)h * DH + d) * N_CTX + kt * 64 + key] = L[d][key];
        }
    } else {
        // ---- wconv: w_out (DIM, DIM) fp32 -> bf16 row-major ----
        const int b2 = bid - 33792;
        int i = (b2 * 256 + t) * 4;
        float4 f = *(const float4*)&w[i];
        ushort4 u;
        u.x = f2bf(f.x); u.y = f2bf(f.y); u.z = f2bf(f.z); u.w = f2bf(f.w);
        *(ushort4*)&wb[i] = u;
    }
}

// ---------------------------------------------------------------------------
// attn: MFMA flash attention, P in registers, K=32 PV via permlane assembly.
// 4 query-tiles per wave (R6, verified).  R12: T5 s_setprio(1) around the
// pure-MFMA clusters (S and PV).  Mechanism: between per-tile barriers the
// ~16 resident waves/CU drift across phases (S-MFMA / exp+pack VALU /
// permlane / PV-MFMA); priority biases CU arbitration toward MFMA-ready
// waves so the matrix pipe stays fed (MfmaUtil 28% vs VALU 56%).
// Zero register/numeric cost (SALU).  m191: +4-7% attn; m190: null on
// lockstep GEMM — ours is intermediate; null outcome finalizes R9 config.
// NOTE: no min-waves launch bound — caps spill o_acc (round 1: 970 MB
// scratch writes).  WRITE_SIZE == 33792 KB is the no-spill tripwire.
// ---------------------------------------------------------------------------
__global__ __launch_bounds__(256) void attn_kernel(
    const ushort* __restrict__ qb, const ushort* __restrict__ kb,
    const ushort* __restrict__ vt, ushort* __restrict__ opart,
    float* __restrict__ lpart)
{
    __shared__ ushort Ks[64][72];    // [key][d]
    __shared__ ushort Vt[64][72];    // [d][key]

    const int h     = blockIdx.y;
    const int qbase = blockIdx.x * 256;
    const int sp    = blockIdx.z;
    const int kbase = sp * (N_CTX / NSPLIT);
    const int t    = threadIdx.x;
    const int w    = t >> 6;
    const int lane = t & 63;
    const int l15  = lane & 15;
    const int quad = lane >> 4;

    // Q B-fragments: 4 query-tiles x 2 k-halves (queries w*64 + qt*16 + l15)
    bf16x8 qf[4][2];
    #pragma unroll
    for (int qt = 0; qt < 4; qt++) {
        const size_t qrow = ((size_t)h * N_CTX + qbase + w * 64 + qt * 16 + l15) * DH;
        qf[qt][0] = *(const bf16x8*)&qb[qrow + quad * 8];
        qf[qt][1] = *(const bf16x8*)&qb[qrow + 32 + quad * 8];
    }

    float l_part[4] = {0.f, 0.f, 0.f, 0.f};
    f32x4 o_acc[4][4];               // [dt][qt]
    #pragma unroll
    for (int dt = 0; dt < 4; dt++)
        #pragma unroll
        for (int qt = 0; qt < 4; qt++)
            o_acc[dt][qt] = (f32x4){0.f, 0.f, 0.f, 0.f};

    // staging: 256 threads, 2 x 16B chunks each of K and V (rows sr, sr+32)
    const int sr = t >> 3;
    const int sc = (t & 7) * 8;
    const ushort* kp0 = &kb[((size_t)h * N_CTX + kbase + sr) * DH + sc];
    const ushort* kp1 = kp0 + (size_t)32 * DH;
    const ushort* vp0 = &vt[((size_t)h * DH + sr) * N_CTX + kbase + sc];
    const ushort* vp1 = vp0 + (size_t)32 * N_CTX;
    bf16x8 kr0 = *(const bf16x8*)kp0, kr1 = *(const bf16x8*)kp1;
    bf16x8 vr0 = *(const bf16x8*)vp0, vr1 = *(const bf16x8*)vp1;

    for (int kt = 0; kt < KT_PER_SPLIT; kt++) {
        __syncthreads();                       // A: all waves done with prev tile
        *(bf16x8*)&Ks[sr][sc]      = kr0;
        *(bf16x8*)&Ks[sr + 32][sc] = kr1;
        *(bf16x8*)&Vt[sr][sc]      = vr0;
        *(bf16x8*)&Vt[sr + 32][sc] = vr1;
        __syncthreads();                       // B: staging visible
        if (kt + 1 < KT_PER_SPLIT) {           // prefetch next tile into regs
            kr0 = *(const bf16x8*)(kp0 + (size_t)(kt + 1) * 64 * DH);
            kr1 = *(const bf16x8*)(kp1 + (size_t)(kt + 1) * 64 * DH);
            vr0 = *(const bf16x8*)(vp0 + (size_t)(kt + 1) * 64);
            vr1 = *(const bf16x8*)(vp1 + (size_t)(kt + 1) * 64);
        }

        // ---- fused S+PV over 2 key-subtile PAIRS (32 keys each)
        #pragma unroll
        for (int jp = 0; jp < 2; jp++) {
            unsigned pa[4][2], pb[4][2];   // [qt][dword]: subtile jj=0 / jj=1
            #pragma unroll
            for (int jj = 0; jj < 2; jj++) {
                const int j = jp * 2 + jj;
                bf16x8 kf0 = *(const bf16x8*)&Ks[j * 16 + l15][quad * 8];
                bf16x8 kf1 = *(const bf16x8*)&Ks[j * 16 + l15][32 + quad * 8];
                f32x4 sv[4];
                #pragma unroll
                for (int qt = 0; qt < 4; qt++)
                    sv[qt] = (f32x4){0.f, 0.f, 0.f, 0.f};
                __builtin_amdgcn_s_setprio(1);         // T5: S-MFMA cluster
                #pragma unroll
                for (int qt = 0; qt < 4; qt++)
                    sv[qt] = __builtin_amdgcn_mfma_f32_16x16x32_bf16(kf0, qf[qt][0], sv[qt], 0, 0, 0);
                #pragma unroll
                for (int qt = 0; qt < 4; qt++)
                    sv[qt] = __builtin_amdgcn_mfma_f32_16x16x32_bf16(kf1, qf[qt][1], sv[qt], 0, 0, 0);
                __builtin_amdgcn_s_setprio(0);

                #pragma unroll
                for (int qt = 0; qt < 4; qt++) {
                    float p0 = fast_exp2(sv[qt].x), p1 = fast_exp2(sv[qt].y);
                    float p2 = fast_exp2(sv[qt].z), p3 = fast_exp2(sv[qt].w);
                    l_part[qt] += (p0 + p1) + (p2 + p3);
                    unsigned d0 = pack_bf16(p0, p1), d1 = pack_bf16(p2, p3);
                    if (jj == 0) { pa[qt][0] = d0; pa[qt][1] = d1; }
                    else         { pb[qt][0] = d0; pb[qt][1] = d1; }
                }
            }

            // assemble K=32 B-fragments in-register (4 permlane ops per qt)
            bf16x8 pw[4];
            #pragma unroll
            for (int qt = 0; qt < 4; qt++) {
                unsigned x0 = pa[qt][0], y0 = pb[qt][0];
                unsigned x1 = pa[qt][1], y1 = pb[qt][1];
                pl32_swap(x0, y0);
                pl32_swap(x1, y1);
                pl16_swap(x0, y0);   // x0 = W0 (k 8q+0,1), y0 = W2 (k 8q+4,5)
                pl16_swap(x1, y1);   // x1 = W1 (k 8q+2,3), y1 = W3 (k 8q+6,7)
                uint4 wd; wd.x = x0; wd.y = x1; wd.z = y0; wd.w = y1;
                pw[qt] = __builtin_bit_cast(bf16x8, wd);
            }

            // PV at K=32: vf (A-operand, A[row=d=l15][k=quad*8+i]) shared by
            // all 4 query-tiles.  O layout matches prior rounds.
            __builtin_amdgcn_s_setprio(1);             // T5: PV-MFMA cluster
            #pragma unroll
            for (int dt = 0; dt < 4; dt++) {
                bf16x8 vf = *(const bf16x8*)&Vt[dt * 16 + l15][jp * 32 + quad * 8];
                #pragma unroll
                for (int qt = 0; qt < 4; qt++)
                    o_acc[dt][qt] = __builtin_amdgcn_mfma_f32_16x16x32_bf16(vf, pw[qt], o_acc[dt][qt], 0, 0, 0);
            }
            __builtin_amdgcn_s_setprio(0);
        }
    }

    // l: reduce across quads (disjoint key subsets per quad)
    #pragma unroll
    for (int qt = 0; qt < 4; qt++) {
        float v = l_part[qt];
        v += __shfl_xor(v, 16, 64);
        v += __shfl_xor(v, 32, 64);
        if (quad == 0)
            lpart[(size_t)sp * NH * N_CTX + (size_t)h * N_CTX
                  + qbase + w * 64 + qt * 16 + l15] = v;
    }

    // O partial (pre-division), bf16 [sp][N][DIM]
    #pragma unroll
    for (int qt = 0; qt < 4; qt++)
        #pragma unroll
        for (int dt = 0; dt < 4; dt++) {
            f32x4 o = o_acc[dt][qt];
            ushort4 ov;
            ov.x = f2bf(o.x); ov.y = f2bf(o.y);
            ov.z = f2bf(o.z); ov.w = f2bf(o.w);
            *(ushort4*)&opart[((size_t)sp * N_CTX + qbase + w * 64 + qt * 16 + l15) * DIM
                              + h * DH + dt * 16 + quad * 4] = ov;
        }
}

// ---------------------------------------------------------------------------
// combine: attnb[n][c] = bf16( (sum_sp O_sp)[n][c] / (sum_sp l_sp)[n,h] )
// ---------------------------------------------------------------------------
__global__ __launch_bounds__(256) void combine_kernel(
    const ushort* __restrict__ opart, const float* __restrict__ lpart,
    ushort* __restrict__ attnb)
{
    const int idx = blockIdx.x * 256 + threadIdx.x;   // one per 4 elements
    const int n   = idx >> 8;
    const int rem = idx & 255;
    const int h   = rem >> 4;
    const size_t e = (size_t)n * DIM + h * DH + (rem & 15) * 4;

    float s0 = 0.f, s1 = 0.f, s2 = 0.f, s3 = 0.f, lsum = 0.f;
    #pragma unroll
    for (int sp = 0; sp < NSPLIT; sp++) {
        ushort4 u = *(const ushort4*)&opart[(size_t)sp * N_CTX * DIM + e];
        s0 += bf2f(u.x); s1 += bf2f(u.y); s2 += bf2f(u.z); s3 += bf2f(u.w);
        lsum += lpart[(size_t)sp * NH * N_CTX + (size_t)h * N_CTX + n];
    }
    float li = 1.0f / lsum;

    ushort4 r;
    r.x = f2bf(s0 * li); r.y = f2bf(s1 * li);
    r.z = f2bf(s2 * li); r.w = f2bf(s3 * li);
    *(ushort4*)&attnb[e] = r;
}

// ---------------------------------------------------------------------------
// proj (MFMA): out[n][o] = sum_c A[n][c] * W[o][c] + b[o]
// 128x128 block tile (m93-class): 2:1 MFMA:ds_read, acc[4][4]/wave.
// Grid (32,8) = 256 blocks = exactly 1/CU, no tail.  (R8-verified.)
// ---------------------------------------------------------------------------
__global__ __launch_bounds__(256) void proj_kernel(
    const ushort* __restrict__ A, const ushort* __restrict__ W,
    const float* __restrict__ bias, float* __restrict__ out)
{
    __shared__ ushort As[128][72];
    __shared__ ushort Ws[128][72];

    const int nbase = blockIdx.x * 128;
    const int obase = blockIdx.y * 128;
    const int t    = threadIdx.x;
    const int w    = t >> 6;
    const int lane = t & 63;
    const int l15  = lane & 15;
    const int quad = lane >> 4;
    const int rw   = (w >> 1) * 64;
    const int cw   = (w & 1) * 64;

    f32x4 acc[4][4];
    #pragma unroll
    for (int mt = 0; mt < 4; mt++)
        #pragma unroll
        for (int nt = 0; nt < 4; nt++)
            acc[mt][nt] = (f32x4){0.f, 0.f, 0.f, 0.f};

    // staging: 4 x 16B chunks each of A and W; rows srow + i*32, i<4
    const int srow = t >> 3;
    const int scol = (t & 7) * 8;
    const ushort* apt = &A[(size_t)(nbase + srow) * DIM + scol];
    const ushort* wpt = &W[(size_t)(obase + srow) * DIM + scol];

    bf16x8 ar[4], wr[4];
    #pragma unroll
    for (int i = 0; i < 4; i++) {
        ar[i] = *(const bf16x8*)(apt + (size_t)i * 32 * DIM);
        wr[i] = *(const bf16x8*)(wpt + (size_t)i * 32 * DIM);
    }

    for (int kt = 0; kt < DIM / 64; kt++) {
        __syncthreads();                       // A: prev tile fully consumed
        #pragma unroll
        for (int i = 0; i < 4; i++) {
            *(bf16x8*)&As[srow + i * 32][scol] = ar[i];
            *(bf16x8*)&Ws[srow + i * 32][scol] = wr[i];
        }
        __syncthreads();                       // B: staging visible
        if (kt + 1 < DIM / 64) {               // prefetch next K-slab
            #pragma unroll
            for (int i = 0; i < 4; i++) {
                ar[i] = *(const bf16x8*)(apt + (size_t)(kt + 1) * 64 + (size_t)i * 32 * DIM);
                wr[i] = *(const bf16x8*)(wpt + (size_t)(kt + 1) * 64 + (size_t)i * 32 * DIM);
            }
        }

        bf16x8 af[4][2], bfr[4][2];
        #pragma unroll
        for (int mt = 0; mt < 4; mt++)
            #pragma unroll
            for (int kh = 0; kh < 2; kh++)
                af[mt][kh] = *(const bf16x8*)&As[rw + mt * 16 + l15][kh * 32 + quad * 8];
        #pragma unroll
        for (int nt = 0; nt < 4; nt++)
            #pragma unroll
            for (int kh = 0; kh < 2; kh++)
                bfr[nt][kh] = *(const bf16x8*)&Ws[cw + nt * 16 + l15][kh * 32 + quad * 8];

        #pragma unroll
        for (int mt = 0; mt < 4; mt++)
            #pragma unroll
            for (int nt = 0; nt < 4; nt++) {
                acc[mt][nt] = __builtin_amdgcn_mfma_f32_16x16x32_bf16(af[mt][0], bfr[nt][0], acc[mt][nt], 0, 0, 0);
                acc[mt][nt] = __builtin_amdgcn_mfma_f32_16x16x32_bf16(af[mt][1], bfr[nt][1], acc[mt][nt], 0, 0, 0);
            }
    }

    #pragma unroll
    for (int nt = 0; nt < 4; nt++) {
        int o = obase + cw + nt * 16 + l15;
        float bb = bias[o];
        #pragma unroll
        for (int mt = 0; mt < 4; mt++) {
            int nrow = nbase + rw + mt * 16 + quad * 4;
            out[(size_t)(nrow + 0) * DIM + o] = acc[mt][nt].x + bb;
            out[(size_t)(nrow + 1) * DIM + o] = acc[mt][nt].y + bb;
            out[(size_t)(nrow + 2) * DIM + o] = acc[mt][nt].z + bb;
            out[(size_t)(nrow + 3) * DIM + o] = acc[mt][nt].w + bb;
        }
    }
}

// ---------------------------------------------------------------------------
extern "C" void kernel_launch(void* const* d_in, const int* in_sizes, int n_in,
                              void* d_out, int out_size, void* d_ws, size_t ws_size,
                              hipStream_t stream)
{
    const float* q        = (const float*)d_in[0];
    const float* k        = (const float*)d_in[1];
    const float* v        = (const float*)d_in[2];
    const float* qk_scale = (const float*)d_in[3];
    const float* w_out    = (const float*)d_in[4];
    const float* b_out    = (const float*)d_in[5];
    float* out = (float*)d_out;

    const size_t per = (size_t)NH * N_CTX * DH;      // 4.19M elements
    ushort* qb    = (ushort*)d_ws;
    ushort* kb    = qb + per;
    ushort* vtg   = kb + per;
    ushort* attnb = vtg + per;                       // (N, DIM) bf16
    ushort* wb    = attnb + per;                     // (DIM, DIM) bf16
    ushort* opart = wb + (size_t)DIM * DIM;          // NSPLIT x (N, DIM) bf16
    float*  lpart = (float*)(opart + (size_t)NSPLIT * N_CTX * DIM);

    // 4 launches: front = prep-q | prep-k | vtrans | wconv fused (R9).
    front_kernel<<<dim3(34816), 256, 0, stream>>>(q, k, v, w_out, qk_scale,
                                                  qb, kb, vtg, wb);
    attn_kernel<<<dim3(N_CTX / 256, NH, NSPLIT), 256, 0, stream>>>(qb, kb, vtg, opart, lpart);
    combine_kernel<<<dim3(N_CTX * DIM / 4 / 256), 256, 0, stream>>>(opart, lpart, attnb);
    proj_kernel<<<dim3(N_CTX / 128, DIM / 128), 256, 0, stream>>>(attnb, wb, b_out, out);
}

// Round 13
// 232.529 us; speedup vs baseline: 1.0182x; 1.0182x over previous
//
#include <hip/hip_runtime.h>
#include <hip/hip_bf16.h>

#define N_CTX 4096
#define NH    16
#define DH    64
#define DIM   1024   // NH * DH
#define NSPLIT 4
#define KT_PER_SPLIT (N_CTX / 64 / NSPLIT)   // 16

typedef __attribute__((ext_vector_type(8))) short bf16x8;  // 8 bf16 in 4 VGPRs
typedef __attribute__((ext_vector_type(4))) float f32x4;   // MFMA C/D
typedef __attribute__((ext_vector_type(2))) unsigned u32x2;

// RNE float->bf16 (non-hot paths)
__device__ __forceinline__ ushort f2bf(float f) {
    union { float f; unsigned u; } x; x.f = f;
    unsigned r = (x.u + 0x7FFFu + ((x.u >> 16) & 1u)) >> 16;
    return (ushort)r;
}
__device__ __forceinline__ float bf2f(ushort u) {
    union { unsigned u; float f; } x; x.u = ((unsigned)u) << 16; return x.f;
}
__device__ __forceinline__ unsigned fbits(float f) {
    union { float f; unsigned u; } x; x.f = f; return x.u;
}
// pack two floats to packed bf16 pair (round-half-up), 3 VALU ops.
// VERIFIED R0-R11.  Failed experiments, do not repeat:
//   R7:  v_cvt_pk_bf16_f32 swap — absmax 20x regression (semantics mismatch).
//   R10: l via ones-MFMA — VGPR 112->156, occupancy 19->11%, +27 µs.
//   R12: s_setprio around MFMA clusters — +5 µs (barrier-lockstep waves;
//        priority starves the dominant VALU phase; m190-class null).
__device__ __forceinline__ unsigned pack_bf16(float lo, float hi) {
    unsigned a = fbits(lo) + 0x8000u;
    unsigned b = fbits(hi) + 0x8000u;
#if defined(__has_builtin)
#if __has_builtin(__builtin_amdgcn_perm)
    return __builtin_amdgcn_perm(b, a, 0x07060302u);
#else
    return (a >> 16) | (b & 0xFFFF0000u);
#endif
#else
    return (a >> 16) | (b & 0xFFFF0000u);
#endif
}
__device__ __forceinline__ float fast_exp2(float x) {
#if defined(__has_builtin)
#if __has_builtin(__builtin_amdgcn_exp2f)
    return __builtin_amdgcn_exp2f(x);
#else
    return exp2f(x);
#endif
#else
    return exp2f(x);
#endif
}
// hw sin/cos of x (radians): revolutions + v_fract + v_sin/v_cos.
__device__ __forceinline__ void fast_sincos(float ang, float* s, float* c) {
#if defined(__has_builtin)
#if __has_builtin(__builtin_amdgcn_sinf) && __has_builtin(__builtin_amdgcn_cosf) && __has_builtin(__builtin_amdgcn_fractf)
    float rev = __builtin_amdgcn_fractf(ang * 0.15915494309189535f);
    *s = __builtin_amdgcn_sinf(rev);
    *c = __builtin_amdgcn_cosf(rev);
    return;
#endif
#endif
    sincosf(ang, s, c);
}

// Cross-lane row swaps (gfx950 VALU ops, 2 outputs per instruction).
__device__ __forceinline__ void pl32_swap(unsigned &a, unsigned &b) {
#if defined(__has_builtin)
#if __has_builtin(__builtin_amdgcn_permlane32_swap)
    u32x2 r = __builtin_amdgcn_permlane32_swap(a, b, false, false);
    a = r[0]; b = r[1];
    return;
#endif
#endif
    const int lane = (int)(threadIdx.x & 63);
    unsigned ax = (unsigned)__shfl_xor((int)a, 32, 64);
    unsigned bx = (unsigned)__shfl_xor((int)b, 32, 64);
    unsigned na = (lane & 32) ? bx : a;
    unsigned nb = (lane & 32) ? b  : ax;
    a = na; b = nb;
}
__device__ __forceinline__ void pl16_swap(unsigned &a, unsigned &b) {
#if defined(__has_builtin)
#if __has_builtin(__builtin_amdgcn_permlane16_swap)
    u32x2 r = __builtin_amdgcn_permlane16_swap(a, b, false, false);
    a = r[0]; b = r[1];
    return;
#endif
#endif
    const int lane = (int)(threadIdx.x & 63);
    unsigned ax = (unsigned)__shfl_xor((int)a, 16, 64);
    unsigned bx = (unsigned)__shfl_xor((int)b, 16, 64);
    unsigned na = (lane & 16) ? bx : a;
    unsigned nb = (lane & 16) ? b  : ax;
    a = na; b = nb;
}

// 0.125 * log2(e): folded into Q during prep; softmax shift-invariance lets us
// drop the bias term entirely (p = exp2(s) directly, p <= 2^18.1).
#define SC 0.18033688011112042f
// log2(10000)/32
#define LF 0.4152410118609203f

// ---------------------------------------------------------------------------
// front (fused): prep-q | prep-k | vtrans | wconv in ONE launch (R9).
//   bid [0,16384)      : prep q  (premul SC)
//   bid [16384,32768)  : prep k
//   bid [32768,33792)  : vtrans (kt = b&63, h = b>>6)
//   bid [33792,34816)  : wconv
// ---------------------------------------------------------------------------
__global__ __launch_bounds__(256) void front_kernel(
    const float* __restrict__ qg, const float* __restrict__ kg,
    const float* __restrict__ v,  const float* __restrict__ w,
    const float* __restrict__ qk_scale,
    ushort* __restrict__ qb, ushort* __restrict__ kb,
    ushort* __restrict__ vt, ushort* __restrict__ wb)
{
    __shared__ ushort L[64][68];
    const int bid = blockIdx.x;
    const int t   = threadIdx.x;

    if (bid < 32768) {
        // ---- prep (R5-verified body: per-thread sincos) ----
        const int isk  = bid >> 14;
        const int bx   = bid & 16383;
        const int lane = t & 63;
        const int wave = t >> 6;
        const int row  = bx * 4 + wave;   // row = n*NH + h
        const int n = row >> 4;
        const int h = row & 15;
        const float* __restrict__ x = isk ? kg : qg;
        ushort* __restrict__ xb = isk ? kb : qb;
        const float premul = isk ? 1.0f : SC;

        float val = x[(size_t)n * DIM + h * DH + lane];
        float other = __shfl_xor(val, 1, 64);

        const int i = lane >> 1;
        float inv_freq = fast_exp2((float)i * -LF);   // 10000^(-i/32)
        float ang = (float)n * inv_freq;
        float s, c;
        fast_sincos(ang, &s, &c);

        float r = (lane & 1) ? fmaf(other, s, val * c)
                             : fmaf(val, c, -(other * s));

        float ss = r * r;
        #pragma unroll
        for (int off = 32; off > 0; off >>= 1)
            ss += __shfl_xor(ss, off, 64);
        float invn = rsqrtf(fmaxf(ss, 1e-24f));
        float scl  = qk_scale[lane] * premul;

        xb[((size_t)h * N_CTX + n) * DH + lane] = f2bf(r * invn * scl);
    } else if (bid < 33792) {
        // ---- vtrans: v (N, DIM) fp32 -> vt bf16 [h][d][n] ----
        const int b2 = bid - 32768;
        const int kt = b2 & 63, h = b2 >> 6;

        for (int e = t; e < 4096; e += 256) {
            int key = e >> 6, d = e & 63;
            float f = v[(size_t)(kt * 64 + key) * DIM + h * DH + d];
            L[d][key] = f2bf(f);
        }
        __syncthreads();
        for (int e = t; e < 4096; e += 256) {
            int d = e >> 6, key = e & 63;
            vt[((size_t)h * DH + d) * N_CTX + kt * 64 + key] = L[d][key];
        }
    } else {
        // ---- wconv: w_out (DIM, DIM) fp32 -> bf16 row-major ----
        const int b2 = bid - 33792;
        int i = (b2 * 256 + t) * 4;
        float4 f = *(const float4*)&w[i];
        ushort4 u;
        u.x = f2bf(f.x); u.y = f2bf(f.y); u.z = f2bf(f.z); u.w = f2bf(f.w);
        *(ushort4*)&wb[i] = u;
    }
}

// ---------------------------------------------------------------------------
// attn: MFMA flash attention, P in registers, K=32 PV via permlane assembly.
// 4 query-tiles per wave (R6, verified: bank-conflict halved exactly).
// FINAL = R9-verified best: 102.7 µs, VGPR 112, bank 4.19e6, occupancy 19.5%.
// No saturated pipe (VALU 56%, MFMA 28%, HBM 14%) — latency-limited local
// minimum of this 2-barrier schedule; all within-structure levers A/B'd.
// NOTE: no min-waves launch bound — caps spill o_acc (round 1: 970 MB
// scratch writes).  WRITE_SIZE == 33792 KB is the no-spill tripwire.
// ---------------------------------------------------------------------------
__global__ __launch_bounds__(256) void attn_kernel(
    const ushort* __restrict__ qb, const ushort* __restrict__ kb,
    const ushort* __restrict__ vt, ushort* __restrict__ opart,
    float* __restrict__ lpart)
{
    __shared__ ushort Ks[64][72];    // [key][d]
    __shared__ ushort Vt[64][72];    // [d][key]

    const int h     = blockIdx.y;
    const int qbase = blockIdx.x * 256;
    const int sp    = blockIdx.z;
    const int kbase = sp * (N_CTX / NSPLIT);
    const int t    = threadIdx.x;
    const int w    = t >> 6;
    const int lane = t & 63;
    const int l15  = lane & 15;
    const int quad = lane >> 4;

    // Q B-fragments: 4 query-tiles x 2 k-halves (queries w*64 + qt*16 + l15)
    bf16x8 qf[4][2];
    #pragma unroll
    for (int qt = 0; qt < 4; qt++) {
        const size_t qrow = ((size_t)h * N_CTX + qbase + w * 64 + qt * 16 + l15) * DH;
        qf[qt][0] = *(const bf16x8*)&qb[qrow + quad * 8];
        qf[qt][1] = *(const bf16x8*)&qb[qrow + 32 + quad * 8];
    }

    float l_part[4] = {0.f, 0.f, 0.f, 0.f};
    f32x4 o_acc[4][4];               // [dt][qt]
    #pragma unroll
    for (int dt = 0; dt < 4; dt++)
        #pragma unroll
        for (int qt = 0; qt < 4; qt++)
            o_acc[dt][qt] = (f32x4){0.f, 0.f, 0.f, 0.f};

    // staging: 256 threads, 2 x 16B chunks each of K and V (rows sr, sr+32)
    const int sr = t >> 3;
    const int sc = (t & 7) * 8;
    const ushort* kp0 = &kb[((size_t)h * N_CTX + kbase + sr) * DH + sc];
    const ushort* kp1 = kp0 + (size_t)32 * DH;
    const ushort* vp0 = &vt[((size_t)h * DH + sr) * N_CTX + kbase + sc];
    const ushort* vp1 = vp0 + (size_t)32 * N_CTX;
    bf16x8 kr0 = *(const bf16x8*)kp0, kr1 = *(const bf16x8*)kp1;
    bf16x8 vr0 = *(const bf16x8*)vp0, vr1 = *(const bf16x8*)vp1;

    for (int kt = 0; kt < KT_PER_SPLIT; kt++) {
        __syncthreads();                       // A: all waves done with prev tile
        *(bf16x8*)&Ks[sr][sc]      = kr0;
        *(bf16x8*)&Ks[sr + 32][sc] = kr1;
        *(bf16x8*)&Vt[sr][sc]      = vr0;
        *(bf16x8*)&Vt[sr + 32][sc] = vr1;
        __syncthreads();                       // B: staging visible
        if (kt + 1 < KT_PER_SPLIT) {           // prefetch next tile into regs
            kr0 = *(const bf16x8*)(kp0 + (size_t)(kt + 1) * 64 * DH);
            kr1 = *(const bf16x8*)(kp1 + (size_t)(kt + 1) * 64 * DH);
            vr0 = *(const bf16x8*)(vp0 + (size_t)(kt + 1) * 64);
            vr1 = *(const bf16x8*)(vp1 + (size_t)(kt + 1) * 64);
        }

        // ---- fused S+PV over 2 key-subtile PAIRS (32 keys each)
        #pragma unroll
        for (int jp = 0; jp < 2; jp++) {
            unsigned pa[4][2], pb[4][2];   // [qt][dword]: subtile jj=0 / jj=1
            #pragma unroll
            for (int jj = 0; jj < 2; jj++) {
                const int j = jp * 2 + jj;
                bf16x8 kf0 = *(const bf16x8*)&Ks[j * 16 + l15][quad * 8];
                bf16x8 kf1 = *(const bf16x8*)&Ks[j * 16 + l15][32 + quad * 8];
                f32x4 sv[4];
                #pragma unroll
                for (int qt = 0; qt < 4; qt++)
                    sv[qt] = (f32x4){0.f, 0.f, 0.f, 0.f};
                #pragma unroll
                for (int qt = 0; qt < 4; qt++)
                    sv[qt] = __builtin_amdgcn_mfma_f32_16x16x32_bf16(kf0, qf[qt][0], sv[qt], 0, 0, 0);
                #pragma unroll
                for (int qt = 0; qt < 4; qt++)
                    sv[qt] = __builtin_amdgcn_mfma_f32_16x16x32_bf16(kf1, qf[qt][1], sv[qt], 0, 0, 0);

                #pragma unroll
                for (int qt = 0; qt < 4; qt++) {
                    float p0 = fast_exp2(sv[qt].x), p1 = fast_exp2(sv[qt].y);
                    float p2 = fast_exp2(sv[qt].z), p3 = fast_exp2(sv[qt].w);
                    l_part[qt] += (p0 + p1) + (p2 + p3);
                    unsigned d0 = pack_bf16(p0, p1), d1 = pack_bf16(p2, p3);
                    if (jj == 0) { pa[qt][0] = d0; pa[qt][1] = d1; }
                    else         { pb[qt][0] = d0; pb[qt][1] = d1; }
                }
            }

            // assemble K=32 B-fragments in-register (4 permlane ops per qt)
            bf16x8 pw[4];
            #pragma unroll
            for (int qt = 0; qt < 4; qt++) {
                unsigned x0 = pa[qt][0], y0 = pb[qt][0];
                unsigned x1 = pa[qt][1], y1 = pb[qt][1];
                pl32_swap(x0, y0);
                pl32_swap(x1, y1);
                pl16_swap(x0, y0);   // x0 = W0 (k 8q+0,1), y0 = W2 (k 8q+4,5)
                pl16_swap(x1, y1);   // x1 = W1 (k 8q+2,3), y1 = W3 (k 8q+6,7)
                uint4 wd; wd.x = x0; wd.y = x1; wd.z = y0; wd.w = y1;
                pw[qt] = __builtin_bit_cast(bf16x8, wd);
            }

            // PV at K=32: vf (A-operand, A[row=d=l15][k=quad*8+i]) shared by
            // all 4 query-tiles.  O layout matches prior rounds.
            #pragma unroll
            for (int dt = 0; dt < 4; dt++) {
                bf16x8 vf = *(const bf16x8*)&Vt[dt * 16 + l15][jp * 32 + quad * 8];
                #pragma unroll
                for (int qt = 0; qt < 4; qt++)
                    o_acc[dt][qt] = __builtin_amdgcn_mfma_f32_16x16x32_bf16(vf, pw[qt], o_acc[dt][qt], 0, 0, 0);
            }
        }
    }

    // l: reduce across quads (disjoint key subsets per quad)
    #pragma unroll
    for (int qt = 0; qt < 4; qt++) {
        float v = l_part[qt];
        v += __shfl_xor(v, 16, 64);
        v += __shfl_xor(v, 32, 64);
        if (quad == 0)
            lpart[(size_t)sp * NH * N_CTX + (size_t)h * N_CTX
                  + qbase + w * 64 + qt * 16 + l15] = v;
    }

    // O partial (pre-division), bf16 [sp][N][DIM]
    #pragma unroll
    for (int qt = 0; qt < 4; qt++)
        #pragma unroll
        for (int dt = 0; dt < 4; dt++) {
            f32x4 o = o_acc[dt][qt];
            ushort4 ov;
            ov.x = f2bf(o.x); ov.y = f2bf(o.y);
            ov.z = f2bf(o.z); ov.w = f2bf(o.w);
            *(ushort4*)&opart[((size_t)sp * N_CTX + qbase + w * 64 + qt * 16 + l15) * DIM
                              + h * DH + dt * 16 + quad * 4] = ov;
        }
}

// ---------------------------------------------------------------------------
// combine: attnb[n][c] = bf16( (sum_sp O_sp)[n][c] / (sum_sp l_sp)[n,h] )
// ---------------------------------------------------------------------------
__global__ __launch_bounds__(256) void combine_kernel(
    const ushort* __restrict__ opart, const float* __restrict__ lpart,
    ushort* __restrict__ attnb)
{
    const int idx = blockIdx.x * 256 + threadIdx.x;   // one per 4 elements
    const int n   = idx >> 8;
    const int rem = idx & 255;
    const int h   = rem >> 4;
    const size_t e = (size_t)n * DIM + h * DH + (rem & 15) * 4;

    float s0 = 0.f, s1 = 0.f, s2 = 0.f, s3 = 0.f, lsum = 0.f;
    #pragma unroll
    for (int sp = 0; sp < NSPLIT; sp++) {
        ushort4 u = *(const ushort4*)&opart[(size_t)sp * N_CTX * DIM + e];
        s0 += bf2f(u.x); s1 += bf2f(u.y); s2 += bf2f(u.z); s3 += bf2f(u.w);
        lsum += lpart[(size_t)sp * NH * N_CTX + (size_t)h * N_CTX + n];
    }
    float li = 1.0f / lsum;

    ushort4 r;
    r.x = f2bf(s0 * li); r.y = f2bf(s1 * li);
    r.z = f2bf(s2 * li); r.w = f2bf(s3 * li);
    *(ushort4*)&attnb[e] = r;
}

// ---------------------------------------------------------------------------
// proj (MFMA): out[n][o] = sum_c A[n][c] * W[o][c] + b[o]
// 128x128 block tile (m93-class): 2:1 MFMA:ds_read, acc[4][4]/wave.
// Grid (32,8) = 256 blocks = exactly 1/CU, no tail.  (R8-verified.)
// ---------------------------------------------------------------------------
__global__ __launch_bounds__(256) void proj_kernel(
    const ushort* __restrict__ A, const ushort* __restrict__ W,
    const float* __restrict__ bias, float* __restrict__ out)
{
    __shared__ ushort As[128][72];
    __shared__ ushort Ws[128][72];

    const int nbase = blockIdx.x * 128;
    const int obase = blockIdx.y * 128;
    const int t    = threadIdx.x;
    const int w    = t >> 6;
    const int lane = t & 63;
    const int l15  = lane & 15;
    const int quad = lane >> 4;
    const int rw   = (w >> 1) * 64;
    const int cw   = (w & 1) * 64;

    f32x4 acc[4][4];
    #pragma unroll
    for (int mt = 0; mt < 4; mt++)
        #pragma unroll
        for (int nt = 0; nt < 4; nt++)
            acc[mt][nt] = (f32x4){0.f, 0.f, 0.f, 0.f};

    // staging: 4 x 16B chunks each of A and W; rows srow + i*32, i<4
    const int srow = t >> 3;
    const int scol = (t & 7) * 8;
    const ushort* apt = &A[(size_t)(nbase + srow) * DIM + scol];
    const ushort* wpt = &W[(size_t)(obase + srow) * DIM + scol];

    bf16x8 ar[4], wr[4];
    #pragma unroll
    for (int i = 0; i < 4; i++) {
        ar[i] = *(const bf16x8*)(apt + (size_t)i * 32 * DIM);
        wr[i] = *(const bf16x8*)(wpt + (size_t)i * 32 * DIM);
    }

    for (int kt = 0; kt < DIM / 64; kt++) {
        __syncthreads();                       // A: prev tile fully consumed
        #pragma unroll
        for (int i = 0; i < 4; i++) {
            *(bf16x8*)&As[srow + i * 32][scol] = ar[i];
            *(bf16x8*)&Ws[srow + i * 32][scol] = wr[i];
        }
        __syncthreads();                       // B: staging visible
        if (kt + 1 < DIM / 64) {               // prefetch next K-slab
            #pragma unroll
            for (int i = 0; i < 4; i++) {
                ar[i] = *(const bf16x8*)(apt + (size_t)(kt + 1) * 64 + (size_t)i * 32 * DIM);
                wr[i] = *(const bf16x8*)(wpt + (size_t)(kt + 1) * 64 + (size_t)i * 32 * DIM);
            }
        }

        bf16x8 af[4][2], bfr[4][2];
        #pragma unroll
        for (int mt = 0; mt < 4; mt++)
            #pragma unroll
            for (int kh = 0; kh < 2; kh++)
                af[mt][kh] = *(const bf16x8*)&As[rw + mt * 16 + l15][kh * 32 + quad * 8];
        #pragma unroll
        for (int nt = 0; nt < 4; nt++)
            #pragma unroll
            for (int kh = 0; kh < 2; kh++)
                bfr[nt][kh] = *(const bf16x8*)&Ws[cw + nt * 16 + l15][kh * 32 + quad * 8];

        #pragma unroll
        for (int mt = 0; mt < 4; mt++)
            #pragma unroll
            for (int nt = 0; nt < 4; nt++) {
                acc[mt][nt] = __builtin_amdgcn_mfma_f32_16x16x32_bf16(af[mt][0], bfr[nt][0], acc[mt][nt], 0, 0, 0);
                acc[mt][nt] = __builtin_amdgcn_mfma_f32_16x16x32_bf16(af[mt][1], bfr[nt][1], acc[mt][nt], 0, 0, 0);
            }
    }

    #pragma unroll
    for (int nt = 0; nt < 4; nt++) {
        int o = obase + cw + nt * 16 + l15;
        float bb = bias[o];
        #pragma unroll
        for (int mt = 0; mt < 4; mt++) {
            int nrow = nbase + rw + mt * 16 + quad * 4;
            out[(size_t)(nrow + 0) * DIM + o] = acc[mt][nt].x + bb;
            out[(size_t)(nrow + 1) * DIM + o] = acc[mt][nt].y + bb;
            out[(size_t)(nrow + 2) * DIM + o] = acc[mt][nt].z + bb;
            out[(size_t)(nrow + 3) * DIM + o] = acc[mt][nt].w + bb;
        }
    }
}

// ---------------------------------------------------------------------------
extern "C" void kernel_launch(void* const* d_in, const int* in_sizes, int n_in,
                              void* d_out, int out_size, void* d_ws, size_t ws_size,
                              hipStream_t stream)
{
    const float* q        = (const float*)d_in[0];
    const float* k        = (const float*)d_in[1];
    const float* v        = (const float*)d_in[2];
    const float* qk_scale = (const float*)d_in[3];
    const float* w_out    = (const float*)d_in[4];
    const float* b_out    = (const float*)d_in[5];
    float* out = (float*)d_out;

    const size_t per = (size_t)NH * N_CTX * DH;      // 4.19M elements
    ushort* qb    = (ushort*)d_ws;
    ushort* kb    = qb + per;
    ushort* vtg   = kb + per;
    ushort* attnb = vtg + per;                       // (N, DIM) bf16
    ushort* wb    = attnb + per;                     // (DIM, DIM) bf16
    ushort* opart = wb + (size_t)DIM * DIM;          // NSPLIT x (N, DIM) bf16
    float*  lpart = (float*)(opart + (size_t)NSPLIT * N_CTX * DIM);

    // 4 launches: front = prep-q | prep-k | vtrans | wconv fused (R9).
    front_kernel<<<dim3(34816), 256, 0, stream>>>(q, k, v, w_out, qk_scale,
                                                  qb, kb, vtg, wb);
    attn_kernel<<<dim3(N_CTX / 256, NH, NSPLIT), 256, 0, stream>>>(qb, kb, vtg, opart, lpart);
    combine_kernel<<<dim3(N_CTX * DIM / 4 / 256), 256, 0, stream>>>(opart, lpart, attnb);
    proj_kernel<<<dim3(N_CTX / 128, DIM / 128), 256, 0, stream>>>(attnb, wb, b_out, out);
}